// Round 2
// baseline (601.266 us; speedup 1.0000x reference)
//
#include <hip/hip_runtime.h>
#include <cstdint>

#define NROW 6144
#define KDIM 128
#define NLAB 200
#define C_COEF (-0.28719499063341177f)   /* -ln(99)/16 ; A_COEF = 2 exactly */
#define UBV 64.0f

typedef _Float16 f16x8 __attribute__((ext_vector_type(8)));
typedef float f32x4 __attribute__((ext_vector_type(4)));
typedef __attribute__((address_space(1))) const void as1c_void;
typedef __attribute__((address_space(3))) void as3_void;

__device__ __forceinline__ unsigned key_of(float v){
  unsigned b = __float_as_uint(v);
  return (b & 0x80000000u) ? ~b : (b | 0x80000000u);
}
__device__ __forceinline__ float key_dec(unsigned k){
  unsigned b = (k & 0x80000000u) ? (k ^ 0x80000000u) : ~k;
  return __uint_as_float(b);
}
__device__ __forceinline__ float softplus_f(float x){
  return fmaxf(x, 0.f) + __logf(1.f + __expf(-fabsf(x)));
}
__device__ __forceinline__ float waveRedF(float v){
#pragma unroll
  for (int o = 32; o; o >>= 1) v += __shfl_down(v, o, 64);
  return v;
}
__device__ __forceinline__ unsigned waveRedMinU(unsigned v){
#pragma unroll
  for (int o = 32; o; o >>= 1){ unsigned x = __shfl_down(v, o, 64); v = (x < v) ? x : v; }
  return v;
}
__device__ __forceinline__ unsigned waveRedMaxU(unsigned v){
#pragma unroll
  for (int o = 32; o; o >>= 1){ unsigned x = __shfl_down(v, o, 64); v = (x > v) ? x : v; }
  return v;
}

// ---------------- labels + per-label histogram ----------------
__global__ void k_label(const int* __restrict__ y, unsigned char* __restrict__ lab,
                        int* __restrict__ cnt){
  const int row = blockIdx.x;
  const int t = threadIdx.x;
  if (t < NLAB){
    if (y[(size_t)row * NLAB + t] != 0){
      lab[row] = (unsigned char)t;
      atomicAdd(&cnt[t], 1);
    }
  }
}

// ---------------- tanh -> swizzled f16, + quantization-loss partial ----------------
__global__ __launch_bounds__(256) void k_tanh(const float* __restrict__ u,
    _Float16* __restrict__ uhswz, float* __restrict__ accf){
  const int tid = threadIdx.x;
  const int gid = blockIdx.x * 256 + tid;
  const int row = gid >> 4;
  const int h = gid & 15;
  const int g = h ^ (row & 7);
  const float* sp = u + (size_t)row * KDIM + g * 8;
  float q = 0.f;
  f16x8 o;
#pragma unroll
  for (int t = 0; t < 8; t++){
    float th = tanhf(sp[t]);
    float sg = (th > 0.f) ? 1.f : ((th < 0.f) ? -1.f : 0.f);
    float d = th - sg;
    q += d * d;
    o[t] = (_Float16)th;
  }
  *(f16x8*)(uhswz + (size_t)row * KDIM + h * 8) = o;
  q = waveRedF(q);
  __shared__ float qb[4];
  if ((tid & 63) == 0) qb[tid >> 6] = q;
  __syncthreads();
  if (tid == 0) atomicAdd(&accf[0], qb[0] + qb[1] + qb[2] + qb[3]);
}

// ---------------- inner = uh @ uh^T (f16 MFMA, 128x128 tile, K=128 in one stage) ----------------
__global__ __launch_bounds__(256) void k_mm(const _Float16* __restrict__ A,
    float* __restrict__ out, int row0){
  __shared__ __align__(16) _Float16 As[128 * KDIM];
  __shared__ __align__(16) _Float16 Bs[128 * KDIM];
  const int tid = threadIdx.x;
  const int wav = tid >> 6, lane = tid & 63;
  const int bj = blockIdx.x, bi = blockIdx.y;

  const char* Ag = (const char*)(A + (size_t)(row0 + bi * 128) * KDIM);
  const char* Bg = (const char*)(A + (size_t)(bj * 128) * KDIM);
  char* Asb = (char*)As;
  char* Bsb = (char*)Bs;
#pragma unroll
  for (int t = 0; t < 8; t++){
    const int ub = wav * 8192 + t * 1024;
    __builtin_amdgcn_global_load_lds((as1c_void*)(Ag + ub + lane * 16),
                                     (as3_void*)(Asb + ub), 16, 0, 0);
    __builtin_amdgcn_global_load_lds((as1c_void*)(Bg + ub + lane * 16),
                                     (as3_void*)(Bsb + ub), 16, 0, 0);
  }
  __syncthreads();

  const int quad = lane >> 4, l16 = lane & 15;
  const int wm = (wav >> 1) * 64, wn = (wav & 1) * 64;
  f32x4 acc[4][4];
#pragma unroll
  for (int im = 0; im < 4; im++)
#pragma unroll
    for (int in = 0; in < 4; in++)
      acc[im][in] = (f32x4){0.f, 0.f, 0.f, 0.f};

#pragma unroll
  for (int kb = 0; kb < 4; kb++){
    f16x8 af[4], bf[4];
#pragma unroll
    for (int i = 0; i < 4; i++){
      const int m = wm + i * 16 + l16;
      const int gidx = kb * 4 + quad;
      af[i] = *(const f16x8*)(Asb + m * 256 + ((gidx ^ (m & 7)) << 4));
      const int n = wn + i * 16 + l16;
      bf[i] = *(const f16x8*)(Bsb + n * 256 + ((gidx ^ (n & 7)) << 4));
    }
#pragma unroll
    for (int im = 0; im < 4; im++)
#pragma unroll
      for (int in = 0; in < 4; in++)
        acc[im][in] = __builtin_amdgcn_mfma_f32_16x16x32_f16(af[im], bf[in], acc[im][in], 0, 0, 0);
  }

  float* obase = out + (size_t)(bi * 128) * NROW + (size_t)bj * 128;
#pragma unroll
  for (int im = 0; im < 4; im++)
#pragma unroll
    for (int in = 0; in < 4; in++)
#pragma unroll
      for (int r = 0; r < 4; r++){
        const int rl = wm + im * 16 + quad * 4 + r;
        const int cl = wn + in * 16 + l16;
        obase[(size_t)rl * NROW + cl] = acc[im][in][r];
      }
}

// ---------------- per-row stats + loss: adaptive-shift exact select ----------------
// LDS ~31.6 KB -> 5 blocks/CU (vs 52.7 KB / 3 blocks in prior version).
// Full scans: P0 (load+keys+sums), P1 (one 256-bucket cnt+sum histogram),
// P2 (compact candidates, predicated), P3 (loss). Exact tie handling.
__global__ __launch_bounds__(256) void k_stats(const float* __restrict__ buf,
    const unsigned char* __restrict__ lab, const int* __restrict__ cnt,
    float* __restrict__ accf, int* __restrict__ acci, int row0){
  __shared__ __align__(16) float rowv[NROW];      // 24576 B
  __shared__ unsigned simbit[NROW / 32];          // 768 B
  __shared__ float simv[512];                     // 2048 B
  __shared__ unsigned histc[256];                 // 1024 B
  __shared__ float hists[256];                    // 1024 B
  __shared__ float cand[512];                     // 2048 B
  __shared__ float rbuf[16];
  __shared__ unsigned ubuf[8];
  __shared__ int ctlI[6];    // 0:simCount 1:candCount 2:kr 3:cntB 4:ltS 5:gtS
  __shared__ unsigned ctlU[2]; // 0:kLo(new) 1:range(new, inclusive-1)
  __shared__ float ctlF[6];  // 0:sgtAbove 1:cgtAbove 2:pivotD 3:BP 4:BPd 5:pivotS

  const int tid = threadIdx.x;
  const int lane = tid & 63;
  const int wav = tid >> 6;
  const int row = row0 + blockIdx.x;
  const int myl = lab[row];
  const int n_sim = cnt[myl];
  const int n_dis = NROW - n_sim;
  if (n_dis == 0 || n_sim == 0) return;           // uniform exit
  const int k1 = n_dis - (n_dis * 9) / 10;        // tail count (top-10% dissimilar)
  const int k2 = n_sim - (n_sim * 9) / 10;        // head count (bottom-10% similar)

  if (tid < NROW / 32) simbit[tid] = 0;
  if (tid < 6){ ctlI[tid] = (tid == 2) ? k1 : 0; ctlF[tid] = 0.f; }
  __syncthreads();

  // ---- P0: global load -> LDS, sim bitmask, sums, dissim key min/max, sim gather ----
  const float4* src = (const float4*)(buf + (size_t)blockIdx.x * NROW);
  const uchar4* lsrc = (const uchar4*)lab;
  float sumS = 0.f, sumDS = 0.f;
  unsigned kmn = 0xFFFFFFFFu, kmx = 0u;
  for (int t = tid; t < NROW / 4; t += 256){
    float4 v4 = src[t];
    uchar4 l4 = lsrc[t];
    ((float4*)rowv)[t] = v4;
    float vv[4] = {v4.x, v4.y, v4.z, v4.w};
    unsigned char ll[4] = {l4.x, l4.y, l4.z, l4.w};
    unsigned nib = 0;
#pragma unroll
    for (int e = 0; e < 4; e++){
      float v = vv[e];
      if (ll[e] == (unsigned char)myl){
        sumS += v;
        int p = atomicAdd(&ctlI[0], 1);
        if (p < 512) simv[p] = v;
        nib |= 1u << e;
      } else {
        sumDS += v;
        unsigned k = key_of(v);
        kmn = (k < kmn) ? k : kmn;
        kmx = (k > kmx) ? k : kmx;
      }
    }
    if (nib) atomicOr(&simbit[t >> 3], nib << ((t & 7) * 4));
  }
  sumS = waveRedF(sumS); sumDS = waveRedF(sumDS);
  kmn = waveRedMinU(kmn); kmx = waveRedMaxU(kmx);
  if (lane == 0){ rbuf[wav] = sumS; rbuf[4 + wav] = sumDS; ubuf[wav] = kmn; ubuf[4 + wav] = kmx; }
  __syncthreads();
  sumS = rbuf[0] + rbuf[1] + rbuf[2] + rbuf[3];
  sumDS = rbuf[4] + rbuf[5] + rbuf[6] + rbuf[7];
  unsigned kLo = ubuf[0];
  { unsigned a = ubuf[1]; if (a < kLo) kLo = a; a = ubuf[2]; if (a < kLo) kLo = a; a = ubuf[3]; if (a < kLo) kLo = a; }
  unsigned kHi = ubuf[4];
  { unsigned a = ubuf[5]; if (a > kHi) kHi = a; a = ubuf[6]; if (a > kHi) kHi = a; a = ubuf[7]; if (a > kHi) kHi = a; }
  unsigned range = kHi - kLo;                     // inclusive span minus 1
  __syncthreads();

  // ---- narrowing select: k1-th largest dissim (counted from top) ----
  int tiePath = 0, cntB = 0;
  for (int it = 0; it < 5; ++it){
    int shift = 0;
    while ((range >> shift) > 255u) shift++;
    if (tid < 256){ histc[tid] = 0u; hists[tid] = 0.f; }
    __syncthreads();
    for (int t = tid; t < NROW; t += 256){
      if ((simbit[t >> 5] >> (t & 31)) & 1) continue;
      float v = rowv[t];
      unsigned d = key_of(v) - kLo;
      if (d <= range){
        atomicAdd(&histc[d >> shift], 1u);
        atomicAdd(&hists[d >> shift], v);
      }
    }
    __syncthreads();
    if (wav == 0){
      int kr = ctlI[2];
      unsigned c[4]; float s[4];
      int part = 0; float parts = 0.f;
#pragma unroll
      for (int d = 0; d < 4; d++){ c[d] = histc[4 * lane + d]; s[d] = hists[4 * lane + d]; part += (int)c[d]; parts += s[d]; }
      int suf = part; float sufs = parts;
#pragma unroll
      for (int o = 1; o < 64; o <<= 1){
        int x = __shfl_down(suf, o, 64);
        float y = __shfl_down(sufs, o, 64);
        if (lane + o < 64){ suf += x; sufs += y; }
      }
      int cum = suf - part;       // count in buckets above this lane's group
      float cums = sufs - parts;  // sum in buckets above
#pragma unroll
      for (int d = 3; d >= 0; --d){
        if (kr > cum && kr <= cum + (int)c[d]){
          unsigned b = (unsigned)(4 * lane + d);
          ctlI[2] = kr - cum;                 // rank within bucket (from top)
          ctlI[3] = (int)c[d];                // bucket population
          ctlU[0] = kLo + (b << shift);       // new key base
          unsigned w = (shift == 0) ? 0u : ((1u << shift) - 1u);
          unsigned rem = range - (b << shift);
          ctlU[1] = (w < rem) ? w : rem;      // new inclusive range
          ctlF[0] += cums;                    // exact sum of all keys above bucket
          ctlF[1] += (float)cum;              // exact count above bucket
        }
        cum += (int)c[d]; cums += s[d];
      }
    }
    __syncthreads();
    cntB = ctlI[3]; kLo = ctlU[0]; range = ctlU[1];
    if (cntB <= 512) break;
    if (range == 0u){ tiePath = 1; break; }
  }

  float dSum;
  if (!tiePath){
    // ---- compact bucket candidates (predicated scan), exact rank-count select ----
    for (int t = tid; t < NROW; t += 256){
      if ((simbit[t >> 5] >> (t & 31)) & 1) continue;
      float v = rowv[t];
      unsigned d = key_of(v) - kLo;
      if (d <= range){
        int p = atomicAdd(&ctlI[1], 1);
        if (p < 512) cand[p] = v;
      }
    }
    __syncthreads();
    int nc = ctlI[1]; if (nc > 512) nc = 512;
    const int kr = ctlI[2];
    for (int t = tid; t < nc; t += 256){
      float vt = cand[t];
      int gt = 0, eq = 0;
      for (int j = 0; j < nc; j++){
        float vj = cand[j];
        gt += (vj > vt); eq += (vj == vt);
      }
      if (gt < kr && kr <= gt + eq){ ctlF[2] = vt; ctlI[5] = gt; }
    }
    __syncthreads();
    const float piv = ctlF[2];
    const int gtS = ctlI[5];
    float sgtc = 0.f;
    for (int t = tid; t < nc; t += 256){
      float v = cand[t];
      if (v > piv) sgtc += v;
    }
    sgtc = waveRedF(sgtc);
    if (lane == 0) rbuf[wav] = sgtc;
    __syncthreads();
    sgtc = rbuf[0] + rbuf[1] + rbuf[2] + rbuf[3];
    dSum = ctlF[0] + sgtc + (float)(kr - gtS) * piv;
  } else {
    // all remaining candidates share one exact key value
    dSum = ctlF[0] + (float)ctlI[2] * key_dec(kLo);
  }
  __syncthreads();

  // ---- sMin: k2-th smallest similar, exact rank-count on gathered list ----
  int ns = ctlI[0]; if (ns > 512) ns = 512;
  for (int t = tid; t < ns; t += 256){
    float vt = simv[t];
    int lt = 0, eq = 0;
    for (int j = 0; j < ns; j++){
      float vj = simv[j];
      lt += (vj < vt); eq += (vj == vt);
    }
    if (lt < k2 && k2 <= lt + eq){ ctlF[5] = vt; ctlI[4] = lt; }
  }
  __syncthreads();
  const float piv2 = ctlF[5];
  const int ltS = ctlI[4];
  float slt = 0.f;
  for (int t = tid; t < ns; t += 256){
    float v = simv[t];
    if (v < piv2) slt += v;
  }
  slt = waveRedF(slt);
  if (lane == 0) rbuf[wav] = slt;
  __syncthreads();
  slt = rbuf[0] + rbuf[1] + rbuf[2] + rbuf[3];
  const float sSum = slt + (float)(k2 - ltS) * piv2;

  if (tid == 0){
    float meanS = fminf(fmaxf(sumS / fmaxf((float)n_sim, 1.f), 0.f), UBV);
    float meanDS = fminf(fmaxf(sumDS / fmaxf((float)n_dis, 1.f), 0.f), UBV);
    float dMax = fminf(fmaxf(dSum / fmaxf((float)k1, 1.f), 0.f), UBV);
    float sMin = fminf(fmaxf(sSum / fmaxf((float)k2, 1.f), 0.f), UBV);
    ctlF[3] = meanS - (UBV - meanS) / UBV * fabsf(meanS - dMax);   // BP
    ctlF[4] = meanDS + meanDS / UBV * fabsf(meanDS - sMin);        // BPd
  }
  __syncthreads();

  // ---- loss pass ----
  const float BP = ctlF[3], BPd = ctlF[4];
  float ap = 0.f, an = 0.f, cp = 0.f, cn = 0.f;
  for (int t = tid; t < NROW; t += 256){
    float v = rowv[t];
    bool sim = (simbit[t >> 5] >> (t & 31)) & 1;
    if (sim){
      if (v != BP){
        float dc = v - BP;
        float f = (v > BP) ? C_COEF * dc : (2.f * C_COEF) * dc;
        ap += softplus_f(f); cp += 1.f;
      }
    } else {
      if (v != BPd){
        float dcd = v - BPd;
        float f = (v < BPd) ? C_COEF * dcd : (2.f * C_COEF) * dcd;
        an += softplus_f(-f); cn += 1.f;
      }
    }
  }
  ap = waveRedF(ap); an = waveRedF(an); cp = waveRedF(cp); cn = waveRedF(cn);
  if (lane == 0){ rbuf[wav] = ap; rbuf[4 + wav] = an; rbuf[8 + wav] = cp; rbuf[12 + wav] = cn; }
  __syncthreads();
  if (tid == 0){
    ap = rbuf[0] + rbuf[1] + rbuf[2] + rbuf[3];
    an = rbuf[4] + rbuf[5] + rbuf[6] + rbuf[7];
    cp = rbuf[8] + rbuf[9] + rbuf[10] + rbuf[11];
    cn = rbuf[12] + rbuf[13] + rbuf[14] + rbuf[15];
    atomicAdd(&accf[1], ap / fmaxf(cp, 1.f));
    atomicAdd(&accf[2], an / fmaxf(cn, 1.f));
    atomicAdd(&acci[3], 1);
  }
}

__global__ void k_final(const float* __restrict__ accf, const int* __restrict__ acci,
                        float* __restrict__ out){
  if (threadIdx.x == 0 && blockIdx.x == 0){
    int c = acci[3];
    float posL = 0.f, navL = 0.f;
    if (c > 0){ posL = accf[1] / (float)c; navL = accf[2] / (float)c; }
    out[0] = posL + navL + 0.1f * (accf[0] / (float)(NROW * KDIM));
  }
}

extern "C" void kernel_launch(void* const* d_in, const int* in_sizes, int n_in,
                              void* d_out, int out_size, void* d_ws, size_t ws_size,
                              hipStream_t stream){
  const float* u = (const float*)d_in[0];
  const int* y = (const int*)d_in[1];
  char* ws = (char*)d_ws;
  float* accf = (float*)ws;                       // [0]=qSum [1]=posSum [2]=negSum
  int* acci = (int*)ws;                           // [3]=validCount
  int* cnt = (int*)(ws + 64);                     // 256 ints
  unsigned char* lab = (unsigned char*)(ws + 4096);
  _Float16* uhswz = (_Float16*)(ws + 16384);
  const size_t ibufOff = 16384 + (size_t)NROW * KDIM * 2;
  float* ibuf = (float*)(ws + ibufOff);

  hipMemsetAsync(d_ws, 0, 4096, stream);
  k_label<<<NROW, 256, 0, stream>>>(y, lab, cnt);
  k_tanh<<<(NROW * 16) / 256, 256, 0, stream>>>(u, uhswz, accf);

  size_t avail = (ws_size > ibufOff) ? ws_size - ibufOff : 0;
  long maxRows = (long)(avail / ((size_t)NROW * 4));
  maxRows = (maxRows / 128) * 128;
  if (maxRows > NROW) maxRows = NROW;
  if (maxRows < 128) maxRows = 128;

  for (int r0 = 0; r0 < NROW; r0 += (int)maxRows){
    int rows = NROW - r0;
    if (rows > maxRows) rows = (int)maxRows;
    k_mm<<<dim3(48, rows / 128), 256, 0, stream>>>(uhswz, ibuf, r0);
    k_stats<<<rows, 256, 0, stream>>>(ibuf, lab, cnt, accf, acci, r0);
  }
  k_final<<<1, 64, 0, stream>>>(accf, acci, (float*)d_out);
}

// Round 3
// 366.341 us; speedup vs baseline: 1.6413x; 1.6413x over previous
//
#include <hip/hip_runtime.h>
#include <cstdint>

#define NROW 6144
#define KDIM 128
#define NLAB 200
#define C_COEF (-0.28719499063341177f)   /* -ln(99)/16 ; A_COEF = 2 exactly */
#define UBV 64.0f

typedef _Float16 f16x8 __attribute__((ext_vector_type(8)));
typedef float f32x4 __attribute__((ext_vector_type(4)));
typedef __attribute__((address_space(1))) const void as1c_void;
typedef __attribute__((address_space(3))) void as3_void;

__device__ __forceinline__ float softplus_f(float x){
  return fmaxf(x, 0.f) + __logf(1.f + __expf(-fabsf(x)));
}
__device__ __forceinline__ float waveRedF(float v){
#pragma unroll
  for (int o = 32; o; o >>= 1) v += __shfl_down(v, o, 64);
  return v;
}
__device__ __forceinline__ int bucket_of(float v){
  int b = (int)floorf(v * 2.f) + 128;
  return b < 0 ? 0 : (b > 255 ? 255 : b);
}
__device__ __forceinline__ unsigned key16_of(_Float16 h){
  unsigned short b = __builtin_bit_cast(unsigned short, h);
  return (b & 0x8000u) ? (unsigned)((unsigned short)~b) : (unsigned)(b | 0x8000u);
}
__device__ __forceinline__ float key16_dec(unsigned k){
  unsigned short b = (k & 0x8000u) ? (unsigned short)(k & 0x7FFFu)
                                   : (unsigned short)(~k & 0xFFFFu);
  return (float)__builtin_bit_cast(_Float16, b);
}

// ---------------- labels + per-label histogram ----------------
__global__ void k_label(const int* __restrict__ y, unsigned char* __restrict__ lab,
                        int* __restrict__ cnt){
  const int row = blockIdx.x;
  const int t = threadIdx.x;
  if (t < NLAB){
    if (y[(size_t)row * NLAB + t] != 0){
      lab[row] = (unsigned char)t;
      atomicAdd(&cnt[t], 1);
    }
  }
}

// ---------------- tanh -> swizzled f16, + quantization-loss partial ----------------
__global__ __launch_bounds__(256) void k_tanh(const float* __restrict__ u,
    _Float16* __restrict__ uhswz, float* __restrict__ accf){
  const int tid = threadIdx.x;
  const int gid = blockIdx.x * 256 + tid;
  const int row = gid >> 4;
  const int h = gid & 15;
  const int g = h ^ (row & 7);
  const float* sp = u + (size_t)row * KDIM + g * 8;
  float q = 0.f;
  f16x8 o;
#pragma unroll
  for (int t = 0; t < 8; t++){
    float x = sp[t];
    float e2 = __expf(2.f * x);
    float th = 1.f - 2.f * __builtin_amdgcn_rcpf(e2 + 1.f);  // tanh, ~1e-6 err
    float sg = (th > 0.f) ? 1.f : ((th < 0.f) ? -1.f : 0.f);
    float d = th - sg;
    q += d * d;
    o[t] = (_Float16)th;
  }
  *(f16x8*)(uhswz + (size_t)row * KDIM + h * 8) = o;
  q = waveRedF(q);
  __shared__ float qb[4];
  if ((tid & 63) == 0) qb[tid >> 6] = q;
  __syncthreads();
  if (tid == 0) atomicAdd(&accf[0], qb[0] + qb[1] + qb[2] + qb[3]);
}

// ---------------- inner = uh @ uh^T (f16 MFMA, 128x128 tile, K=128 in one stage) ----------------
__global__ __launch_bounds__(256) void k_mm(const _Float16* __restrict__ A,
    float* __restrict__ out, int row0){
  __shared__ __align__(16) _Float16 As[128 * KDIM];
  __shared__ __align__(16) _Float16 Bs[128 * KDIM];
  const int tid = threadIdx.x;
  const int wav = tid >> 6, lane = tid & 63;
  const int bj = blockIdx.x, bi = blockIdx.y;

  const char* Ag = (const char*)(A + (size_t)(row0 + bi * 128) * KDIM);
  const char* Bg = (const char*)(A + (size_t)(bj * 128) * KDIM);
  char* Asb = (char*)As;
  char* Bsb = (char*)Bs;
#pragma unroll
  for (int t = 0; t < 8; t++){
    const int ub = wav * 8192 + t * 1024;
    __builtin_amdgcn_global_load_lds((as1c_void*)(Ag + ub + lane * 16),
                                     (as3_void*)(Asb + ub), 16, 0, 0);
    __builtin_amdgcn_global_load_lds((as1c_void*)(Bg + ub + lane * 16),
                                     (as3_void*)(Bsb + ub), 16, 0, 0);
  }
  __syncthreads();

  const int quad = lane >> 4, l16 = lane & 15;
  const int wm = (wav >> 1) * 64, wn = (wav & 1) * 64;
  f32x4 acc[4][4];
#pragma unroll
  for (int im = 0; im < 4; im++)
#pragma unroll
    for (int in = 0; in < 4; in++)
      acc[im][in] = (f32x4){0.f, 0.f, 0.f, 0.f};

#pragma unroll
  for (int kb = 0; kb < 4; kb++){
    f16x8 af[4], bf[4];
#pragma unroll
    for (int i = 0; i < 4; i++){
      const int m = wm + i * 16 + l16;
      const int gidx = kb * 4 + quad;
      af[i] = *(const f16x8*)(Asb + m * 256 + ((gidx ^ (m & 7)) << 4));
      const int n = wn + i * 16 + l16;
      bf[i] = *(const f16x8*)(Bsb + n * 256 + ((gidx ^ (n & 7)) << 4));
    }
#pragma unroll
    for (int im = 0; im < 4; im++)
#pragma unroll
      for (int in = 0; in < 4; in++)
        acc[im][in] = __builtin_amdgcn_mfma_f32_16x16x32_f16(af[im], bf[in], acc[im][in], 0, 0, 0);
  }

  float* obase = out + (size_t)(bi * 128) * NROW + (size_t)bj * 128;
#pragma unroll
  for (int im = 0; im < 4; im++)
#pragma unroll
    for (int in = 0; in < 4; in++)
#pragma unroll
      for (int r = 0; r < 4; r++){
        const int rl = wm + im * 16 + quad * 4 + r;
        const int cl = wn + in * 16 + l16;
        obase[(size_t)rl * NROW + cl] = acc[im][in][r];
      }
}

// ---------------- per-row stats + loss ----------------
// f16 row in LDS (~18.3 KB total -> 8 blocks/CU). 3 full scans:
// P0 (load+classify+sums+value-bucket count histogram), P2 (compact pivot
// bucket + register tail-sum), loss. Count-only int LDS atomics. Exact-tie
// arithmetic on the f16-rounded values; f16-key narrowing fallback if a
// bucket ever exceeds 512 (not expected on this data, correctness guard).
__global__ __launch_bounds__(256) void k_stats(const float* __restrict__ buf,
    const unsigned char* __restrict__ lab, const int* __restrict__ cnt,
    float* __restrict__ accf, int* __restrict__ acci, int row0){
  __shared__ __align__(16) _Float16 rowh[NROW];   // 12288 B
  __shared__ unsigned char simb[NROW / 8];        // 768 B
  __shared__ float simv[512];                     // 2048 B
  __shared__ float cand[512];                     // 2048 B
  __shared__ int histc[256];                      // 1024 B
  __shared__ float rbuf[16];
  __shared__ int ctlI[8];   // 0:simCount 1:candCount 2:kr 3:cntB 4:pb 5:gtS 6:ltS
  __shared__ float ctlF[8]; // 2:piv 3:BP 4:BPd 5:piv2
  __shared__ unsigned ctlU[2];

  const int tid = threadIdx.x;
  const int lane = tid & 63;
  const int wav = tid >> 6;
  const int row = row0 + blockIdx.x;
  const int myl = lab[row];
  const int n_sim = cnt[myl];
  const int n_dis = NROW - n_sim;
  if (n_dis == 0 || n_sim == 0) return;           // uniform exit
  const int k1 = n_dis - (n_dis * 9) / 10;        // tail count (top-10% dissimilar)
  const int k2 = n_sim - (n_sim * 9) / 10;        // head count (bottom-10% similar)

  histc[tid] = 0;
  if (tid < 8){ ctlI[tid] = 0; ctlF[tid] = 0.f; }
  __syncthreads();                                // A

  // ---- P0: load -> f16 LDS, classify, sums, fused count histogram ----
  const float4* src = (const float4*)(buf + (size_t)blockIdx.x * NROW);
  const uint2* lsrc = (const uint2*)lab;
  float sumS = 0.f, sumDS = 0.f;
#pragma unroll
  for (int it = 0; it < 3; ++it){
    const int g8 = it * 256 + tid;
    float4 va = src[g8 * 2];
    float4 vb = src[g8 * 2 + 1];
    uint2 lw = lsrc[g8];
    float v[8] = {va.x, va.y, va.z, va.w, vb.x, vb.y, vb.z, vb.w};
    unsigned char l8[8];
    l8[0] = (unsigned char)lw.x;        l8[1] = (unsigned char)(lw.x >> 8);
    l8[2] = (unsigned char)(lw.x >> 16);l8[3] = (unsigned char)(lw.x >> 24);
    l8[4] = (unsigned char)lw.y;        l8[5] = (unsigned char)(lw.y >> 8);
    l8[6] = (unsigned char)(lw.y >> 16);l8[7] = (unsigned char)(lw.y >> 24);
    f16x8 h8;
    unsigned m = 0;
#pragma unroll
    for (int e = 0; e < 8; e++){
      _Float16 hh = (_Float16)v[e];
      h8[e] = hh;
      float hv = (float)hh;
      if (l8[e] == (unsigned char)myl){
        m |= 1u << e;
        sumS += hv;
        int p = atomicAdd(&ctlI[0], 1);
        if (p < 512) simv[p] = hv;
      } else {
        sumDS += hv;
        atomicAdd(&histc[bucket_of(hv)], 1);
      }
    }
    *(f16x8*)(rowh + g8 * 8) = h8;
    simb[g8] = (unsigned char)m;
  }
  sumS = waveRedF(sumS); sumDS = waveRedF(sumDS);
  if (lane == 0){ rbuf[wav] = sumS; rbuf[4 + wav] = sumDS; }
  __syncthreads();                                // B
  sumS = rbuf[0] + rbuf[1] + rbuf[2] + rbuf[3];
  sumDS = rbuf[4] + rbuf[5] + rbuf[6] + rbuf[7];

  // ---- pivot bucket select (wave0, descending suffix count) ----
  if (wav == 0){
    int c[4]; int part = 0;
#pragma unroll
    for (int d = 0; d < 4; d++){ c[d] = histc[4 * lane + d]; part += c[d]; }
    int suf = part;
#pragma unroll
    for (int o = 1; o < 64; o <<= 1){
      int x = __shfl_down(suf, o, 64);
      if (lane + o < 64) suf += x;
    }
    int cum = suf - part;                         // count in buckets above group
#pragma unroll
    for (int d = 3; d >= 0; --d){
      if (k1 > cum && k1 <= cum + c[d]){
        ctlI[2] = k1 - cum;                       // rank within bucket (from top)
        ctlI[3] = c[d];                           // bucket population
        ctlI[4] = 4 * lane + d;                   // pivot bucket
      }
      cum += c[d];
    }
  }
  __syncthreads();                                // C
  const int pb = ctlI[4];
  const int cntB = ctlI[3];
  const int kr0 = ctlI[2];

  // ---- P2: compact pivot bucket + register tail-sum of higher buckets ----
  float sAb = 0.f;
#pragma unroll
  for (int it = 0; it < 3; ++it){
    const int g8 = it * 256 + tid;
    f16x8 h8 = *(const f16x8*)(rowh + g8 * 8);
    unsigned m = simb[g8];
#pragma unroll
    for (int e = 0; e < 8; e++){
      if ((m >> e) & 1) continue;
      float hv = (float)h8[e];
      int b = bucket_of(hv);
      if (b > pb) sAb += hv;
      else if (b == pb){
        int p = atomicAdd(&ctlI[1], 1);
        if (p < 512) cand[p] = hv;
      }
    }
  }
  sAb = waveRedF(sAb);
  if (lane == 0) rbuf[8 + wav] = sAb;
  __syncthreads();                                // D
  sAb = rbuf[8] + rbuf[9] + rbuf[10] + rbuf[11];

  float dSum;
  if (cntB <= 512){
    const int nc = ctlI[1];
    for (int t = tid; t < nc; t += 256){
      float vt = cand[t];
      int gt = 0, eq = 0;
      for (int j = 0; j < nc; j++){
        float vj = cand[j];
        gt += (vj > vt); eq += (vj == vt);
      }
      if (gt < kr0 && kr0 <= gt + eq){ ctlF[2] = vt; ctlI[5] = gt; }
    }
    __syncthreads();                              // E
    const float piv = ctlF[2];
    const int gtS = ctlI[5];
    float sg = 0.f;
    for (int t = tid; t < nc; t += 256){
      float v = cand[t];
      if (v > piv) sg += v;
    }
    sg = waveRedF(sg);
    if (lane == 0) rbuf[wav] = sg;
    __syncthreads();                              // F
    sg = rbuf[0] + rbuf[1] + rbuf[2] + rbuf[3];
    dSum = sAb + sg + (float)(kr0 - gtS) * piv;
  } else {
    // fallback: exact f16-key narrowing within bucket pb (rare)
    unsigned kLo = 0u, range = 65535u;
    for (int itr = 0; itr < 4 && range > 0u; ++itr){
      histc[tid] = 0;
      __syncthreads();
      int shift = 0;
      while ((range >> shift) > 255u) shift++;
      for (int g8 = tid; g8 < NROW / 8; g8 += 256){
        f16x8 h8 = *(const f16x8*)(rowh + g8 * 8);
        unsigned m = simb[g8];
#pragma unroll
        for (int e = 0; e < 8; e++){
          if ((m >> e) & 1) continue;
          float hv = (float)h8[e];
          if (bucket_of(hv) != pb) continue;
          unsigned d = key16_of(h8[e]) - kLo;
          if (d <= range) atomicAdd(&histc[d >> shift], 1);
        }
      }
      __syncthreads();
      if (wav == 0){
        int kr = ctlI[2];
        int c[4]; int part = 0;
#pragma unroll
        for (int d = 0; d < 4; d++){ c[d] = histc[4 * lane + d]; part += c[d]; }
        int suf = part;
#pragma unroll
        for (int o = 1; o < 64; o <<= 1){
          int x = __shfl_down(suf, o, 64);
          if (lane + o < 64) suf += x;
        }
        int cum = suf - part;
#pragma unroll
        for (int d = 3; d >= 0; --d){
          if (kr > cum && kr <= cum + c[d]){
            unsigned b = (unsigned)(4 * lane + d);
            ctlI[2] = kr - cum;
            ctlU[0] = kLo + (b << shift);
            unsigned w = (shift == 0) ? 0u : ((1u << shift) - 1u);
            unsigned rem = range - (b << shift);
            ctlU[1] = (w < rem) ? w : rem;
          }
          cum += c[d];
        }
      }
      __syncthreads();
      kLo = ctlU[0]; range = ctlU[1];
    }
    const int krF = ctlI[2];
    const float piv = key16_dec(kLo);
    float sg = 0.f;
    for (int g8 = tid; g8 < NROW / 8; g8 += 256){
      f16x8 h8 = *(const f16x8*)(rowh + g8 * 8);
      unsigned m = simb[g8];
#pragma unroll
      for (int e = 0; e < 8; e++){
        if ((m >> e) & 1) continue;
        float hv = (float)h8[e];
        if (bucket_of(hv) == pb && key16_of(h8[e]) > kLo) sg += hv;
      }
    }
    sg = waveRedF(sg);
    if (lane == 0) rbuf[wav] = sg;
    __syncthreads();
    sg = rbuf[0] + rbuf[1] + rbuf[2] + rbuf[3];
    dSum = sAb + sg + (float)krF * piv;
  }
  __syncthreads();                                // converge

  // ---- sMin: k2-th smallest similar (exact rank-count on gathered list) ----
  int ns = ctlI[0]; if (ns > 512) ns = 512;
  for (int t = tid; t < ns; t += 256){
    float vt = simv[t];
    int lt = 0, eq = 0;
    for (int j = 0; j < ns; j++){
      float vj = simv[j];
      lt += (vj < vt); eq += (vj == vt);
    }
    if (lt < k2 && k2 <= lt + eq){ ctlF[5] = vt; ctlI[6] = lt; }
  }
  __syncthreads();
  const float piv2 = ctlF[5];
  const int ltS = ctlI[6];
  float slt = 0.f;
  for (int t = tid; t < ns; t += 256){
    float v = simv[t];
    if (v < piv2) slt += v;
  }
  slt = waveRedF(slt);
  if (lane == 0) rbuf[wav] = slt;
  __syncthreads();
  slt = rbuf[0] + rbuf[1] + rbuf[2] + rbuf[3];
  const float sSum = slt + (float)(k2 - ltS) * piv2;

  if (tid == 0){
    float meanS = fminf(fmaxf(sumS / fmaxf((float)n_sim, 1.f), 0.f), UBV);
    float meanDS = fminf(fmaxf(sumDS / fmaxf((float)n_dis, 1.f), 0.f), UBV);
    float dMax = fminf(fmaxf(dSum / fmaxf((float)k1, 1.f), 0.f), UBV);
    float sMin = fminf(fmaxf(sSum / fmaxf((float)k2, 1.f), 0.f), UBV);
    ctlF[3] = meanS - (UBV - meanS) / UBV * fabsf(meanS - dMax);   // BP
    ctlF[4] = meanDS + meanDS / UBV * fabsf(meanDS - sMin);        // BPd
  }
  __syncthreads();                                // G

  // ---- loss pass ----
  const float BP = ctlF[3], BPd = ctlF[4];
  float ap = 0.f, an = 0.f, cp = 0.f, cn = 0.f;
#pragma unroll
  for (int it = 0; it < 3; ++it){
    const int g8 = it * 256 + tid;
    f16x8 h8 = *(const f16x8*)(rowh + g8 * 8);
    unsigned m = simb[g8];
#pragma unroll
    for (int e = 0; e < 8; e++){
      float v = (float)h8[e];
      if ((m >> e) & 1){
        if (v != BP){
          float dc = v - BP;
          float f = (v > BP) ? C_COEF * dc : (2.f * C_COEF) * dc;
          ap += softplus_f(f); cp += 1.f;
        }
      } else {
        if (v != BPd){
          float dcd = v - BPd;
          float f = (v < BPd) ? C_COEF * dcd : (2.f * C_COEF) * dcd;
          an += softplus_f(-f); cn += 1.f;
        }
      }
    }
  }
  ap = waveRedF(ap); an = waveRedF(an); cp = waveRedF(cp); cn = waveRedF(cn);
  if (lane == 0){ rbuf[wav] = ap; rbuf[4 + wav] = an; rbuf[8 + wav] = cp; rbuf[12 + wav] = cn; }
  __syncthreads();                                // H
  if (tid == 0){
    ap = rbuf[0] + rbuf[1] + rbuf[2] + rbuf[3];
    an = rbuf[4] + rbuf[5] + rbuf[6] + rbuf[7];
    cp = rbuf[8] + rbuf[9] + rbuf[10] + rbuf[11];
    cn = rbuf[12] + rbuf[13] + rbuf[14] + rbuf[15];
    atomicAdd(&accf[1], ap / fmaxf(cp, 1.f));
    atomicAdd(&accf[2], an / fmaxf(cn, 1.f));
    atomicAdd(&acci[3], 1);
  }
}

__global__ void k_final(const float* __restrict__ accf, const int* __restrict__ acci,
                        float* __restrict__ out){
  if (threadIdx.x == 0 && blockIdx.x == 0){
    int c = acci[3];
    float posL = 0.f, navL = 0.f;
    if (c > 0){ posL = accf[1] / (float)c; navL = accf[2] / (float)c; }
    out[0] = posL + navL + 0.1f * (accf[0] / (float)(NROW * KDIM));
  }
}

extern "C" void kernel_launch(void* const* d_in, const int* in_sizes, int n_in,
                              void* d_out, int out_size, void* d_ws, size_t ws_size,
                              hipStream_t stream){
  const float* u = (const float*)d_in[0];
  const int* y = (const int*)d_in[1];
  char* ws = (char*)d_ws;
  float* accf = (float*)ws;                       // [0]=qSum [1]=posSum [2]=negSum
  int* acci = (int*)ws;                           // [3]=validCount
  int* cnt = (int*)(ws + 64);                     // 256 ints
  unsigned char* lab = (unsigned char*)(ws + 4096);
  _Float16* uhswz = (_Float16*)(ws + 16384);
  const size_t ibufOff = 16384 + (size_t)NROW * KDIM * 2;
  float* ibuf = (float*)(ws + ibufOff);

  hipMemsetAsync(d_ws, 0, 4096, stream);
  k_label<<<NROW, 256, 0, stream>>>(y, lab, cnt);
  k_tanh<<<(NROW * 16) / 256, 256, 0, stream>>>(u, uhswz, accf);

  size_t avail = (ws_size > ibufOff) ? ws_size - ibufOff : 0;
  long maxRows = (long)(avail / ((size_t)NROW * 4));
  maxRows = (maxRows / 128) * 128;
  if (maxRows > NROW) maxRows = NROW;
  if (maxRows < 128) maxRows = 128;

  for (int r0 = 0; r0 < NROW; r0 += (int)maxRows){
    int rows = NROW - r0;
    if (rows > maxRows) rows = (int)maxRows;
    k_mm<<<dim3(48, rows / 128), 256, 0, stream>>>(uhswz, ibuf, r0);
    k_stats<<<rows, 256, 0, stream>>>(ibuf, lab, cnt, accf, acci, r0);
  }
  k_final<<<1, 64, 0, stream>>>(accf, acci, (float*)d_out);
}